// Round 12
// baseline (1016.850 us; speedup 1.0000x reference)
//
#include <hip/hip_runtime.h>

#define N_NODES 100000
#define N_EDGES 1250000
#define IN_F 128
#define OUT_F 64

// ---------------------------------------------------------------------------
// Kernel 1: h = x @ W  (fp32 vector FMA; no fp32 MFMA on CDNA4).
// ---------------------------------------------------------------------------
#define GR 32
__global__ __launch_bounds__(256) void gemm2_k(const float* __restrict__ x,
                                               const float* __restrict__ w,
                                               float* __restrict__ h) {
    __shared__ float wlds[IN_F * OUT_F];   // 32 KB
    __shared__ float xlds[GR * IN_F];      // 16 KB
    const int t = threadIdx.x;

    const float4* w4 = (const float4*)w;
    float4* wl4 = (float4*)wlds;
    #pragma unroll
    for (int i = t; i < IN_F * OUT_F / 4; i += 256) wl4[i] = w4[i];

    const long row0 = (long)blockIdx.x * GR;
    const float4* x4 = (const float4*)(x + row0 * IN_F);
    float4* xl4 = (float4*)xlds;
    #pragma unroll
    for (int i = t; i < GR * IN_F / 4; i += 256) xl4[i] = x4[i];

    __syncthreads();

    const int col = t & 63;
    const int wv  = t >> 6;                // wave id -> rows wv*8 .. wv*8+7
    float acc[8];
    #pragma unroll
    for (int r = 0; r < 8; ++r) acc[r] = 0.f;

    #pragma unroll
    for (int k = 0; k < IN_F; k += 4) {
        const float w0 = wlds[(k + 0) * OUT_F + col];
        const float w1 = wlds[(k + 1) * OUT_F + col];
        const float w2 = wlds[(k + 2) * OUT_F + col];
        const float w3 = wlds[(k + 3) * OUT_F + col];
        #pragma unroll
        for (int r = 0; r < 8; ++r) {
            const float4 xv = *(const float4*)&xlds[(wv * 8 + r) * IN_F + k];
            acc[r] += xv.x * w0 + xv.y * w1 + xv.z * w2 + xv.w * w3;
        }
    }

    #pragma unroll
    for (int r = 0; r < 8; ++r)
        h[(row0 + wv * 8 + r) * OUT_F + col] = acc[r];
}

// ---------------------------------------------------------------------------
// hist -> scan: per-node counts and CSR starts (starts used only at bucket
// granularity; cnt used for the mean).
// ---------------------------------------------------------------------------
__global__ __launch_bounds__(256) void hist_k(const int* __restrict__ dst,
                                              int* __restrict__ cnt) {
    const int e = blockIdx.x * 256 + threadIdx.x;
    if (e >= N_EDGES) return;
    atomicAdd(&cnt[dst[e]], 1);
}

#define SCAN_B 1024   // elements per scan block (256 threads x 4)
__global__ __launch_bounds__(256) void scan1_k(const int* __restrict__ cnt,
                                               int* __restrict__ start,
                                               int* __restrict__ bsum) {
    __shared__ int lds[256];
    const int t = threadIdx.x;
    const int base = blockIdx.x * SCAN_B + t * 4;
    int v0 = 0, v1 = 0, v2 = 0, v3 = 0;
    if (base + 0 < N_NODES) v0 = cnt[base + 0];
    if (base + 1 < N_NODES) v1 = cnt[base + 1];
    if (base + 2 < N_NODES) v2 = cnt[base + 2];
    if (base + 3 < N_NODES) v3 = cnt[base + 3];
    const int s = v0 + v1 + v2 + v3;
    lds[t] = s;
    __syncthreads();
    #pragma unroll
    for (int off = 1; off < 256; off <<= 1) {
        const int add = (t >= off) ? lds[t - off] : 0;
        __syncthreads();
        lds[t] += add;
        __syncthreads();
    }
    const int excl = lds[t] - s;
    if (base + 0 < N_NODES) start[base + 0] = excl;
    if (base + 1 < N_NODES) start[base + 1] = excl + v0;
    if (base + 2 < N_NODES) start[base + 2] = excl + v0 + v1;
    if (base + 3 < N_NODES) start[base + 3] = excl + v0 + v1 + v2;
    if (t == 255) bsum[blockIdx.x] = lds[t];
}

#define NSCAN_BLOCKS ((N_NODES + SCAN_B - 1) / SCAN_B)   // 98
__global__ __launch_bounds__(128) void scan2_k(int* __restrict__ bsum) {
    __shared__ int lds[128];
    const int t = threadIdx.x;
    const int v = (t < NSCAN_BLOCKS) ? bsum[t] : 0;
    lds[t] = v;
    __syncthreads();
    #pragma unroll
    for (int off = 1; off < 128; off <<= 1) {
        const int add = (t >= off) ? lds[t - off] : 0;
        __syncthreads();
        lds[t] += add;
        __syncthreads();
    }
    if (t < NSCAN_BLOCKS) bsum[t] = lds[t] - v;   // exclusive
}

// Coarse buckets: BNODES dst-nodes per bucket. scan3 finalizes node starts
// and seeds the per-bucket write cursors (bpos) at bucket boundaries.
#define BNBITS 7
#define BNODES 128                                  // nodes per bucket
#define NBUCK ((N_NODES + BNODES - 1) / BNODES)     // 782
__global__ __launch_bounds__(256) void scan3_k(int* __restrict__ start,
                                               int* __restrict__ bpos,
                                               const int* __restrict__ bsum) {
    const int i = blockIdx.x * 256 + threadIdx.x;
    if (i >= N_NODES) return;
    const int v = start[i] + bsum[i / SCAN_B];
    start[i] = v;
    if ((i & (BNODES - 1)) == 0) bpos[i >> BNBITS] = v;
}

// Single-pass bucket scatter. Only 782 write cursors (~3 KB of hot lines,
// L2-resident); records within a bucket land contiguously -> full 64B lines,
// no write amplification (round-9 evidence: per-NODE cursors (100k heads,
// 6.4 MB > 4 MB XCD L2) amplified 10 MB -> 80 MB of HBM writes).
// Record: pack = src (17b) | dst_local (7b) << 17 ; w as f32 bits.
__global__ __launch_bounds__(256) void bscatter_k(const int* __restrict__ src,
                                                  const int* __restrict__ dst,
                                                  const float* __restrict__ ew,
                                                  int* __restrict__ bpos,
                                                  uint2* __restrict__ recs) {
    const int e = blockIdx.x * 256 + threadIdx.x;
    if (e >= N_EDGES) return;
    const int d = dst[e];
    const int p = atomicAdd(&bpos[d >> BNBITS], 1);
    const unsigned pack = (unsigned)src[e] | ((unsigned)(d & (BNODES - 1)) << 17);
    recs[p] = make_uint2(pack, __float_as_uint(ew[e]));
}

// ---------------------------------------------------------------------------
// Per-bucket accumulation in LDS (fp32 tile, ds_add_f32 atomics) + fused
// finalize (div/bias/relu). One block per bucket; quarter-wave per edge:
// 16 lanes x float4 gather h[src] (256B coalesced), scale, LDS atomicAdd.
// No global output atomics; out written once, coalesced.
// ---------------------------------------------------------------------------
__global__ __launch_bounds__(256) void accum_lds_k(const float* __restrict__ h,
                                                   const uint2* __restrict__ recs,
                                                   const int* __restrict__ start,
                                                   const int* __restrict__ cnt,
                                                   const float* __restrict__ bias,
                                                   float* __restrict__ out) {
    __shared__ float tile[BNODES][OUT_F];   // 32 KB -> 5 blocks/CU by LDS
    const int b = blockIdx.x;
    const int t = threadIdx.x;

    float4* tz = (float4*)&tile[0][0];
    #pragma unroll
    for (int i = t; i < BNODES * OUT_F / 4; i += 256)
        tz[i] = make_float4(0.f, 0.f, 0.f, 0.f);
    __syncthreads();

    const int s0 = start[b * BNODES];
    const int e1 = (b == NBUCK - 1) ? N_EDGES : start[(b + 1) * BNODES];

    const int lane = t & 63;
    const int wv = t >> 6;          // 4 waves
    const int q  = lane >> 4;       // quarter within wave
    const int ql = lane & 15;

    for (int i = s0 + wv * 4 + q; i < e1; i += 16) {
        const uint2 r = recs[i];
        const unsigned sn = r.x & 0x1FFFFu;
        const int dl = (int)(r.x >> 17);
        const float w = __uint_as_float(r.y);
        const float4 hv = ((const float4*)(h + (size_t)sn * OUT_F))[ql];
        atomicAdd(&tile[dl][ql * 4 + 0], hv.x * w);
        atomicAdd(&tile[dl][ql * 4 + 1], hv.y * w);
        atomicAdd(&tile[dl][ql * 4 + 2], hv.z * w);
        atomicAdd(&tile[dl][ql * 4 + 3], hv.w * w);
    }
    __syncthreads();

    const float4 bb = ((const float4*)bias)[ql];
    for (int r0 = wv * 4 + q; r0 < BNODES; r0 += 16) {
        const int node = b * BNODES + r0;
        if (node >= N_NODES) break;      // only trims the last bucket
        float c = (float)cnt[node];
        if (c < 1.f) c = 1.f;
        const float inv = 1.0f / c;
        float4 v = *(float4*)&tile[r0][ql * 4];
        v.x = v.x * inv + bb.x;
        v.y = v.y * inv + bb.y;
        v.z = v.z * inv + bb.z;
        v.w = v.w * inv + bb.w;
        v.x = v.x > 0.f ? v.x : 0.f;
        v.y = v.y > 0.f ? v.y : 0.f;
        v.z = v.z > 0.f ? v.z : 0.f;
        v.w = v.w > 0.f ? v.w : 0.f;
        ((float4*)(out + (size_t)node * OUT_F))[ql] = v;
    }
}

// ---------------------------------------------------------------------------
// Fallback path (round-1 proven): atomic scatter + finalize. Used only if
// ws_size is too small for the bucket path.
// ---------------------------------------------------------------------------
__global__ __launch_bounds__(256) void scatter_k(const float* __restrict__ h,
                                                 const float* __restrict__ ew,
                                                 const int* __restrict__ src,
                                                 const int* __restrict__ dst,
                                                 float* __restrict__ out,
                                                 float* __restrict__ cnt) {
    const int e = blockIdx.x * 4 + (threadIdx.x >> 6);
    if (e >= N_EDGES) return;
    const int lane = threadIdx.x & 63;
    const int   s = src[e];
    const int   d = dst[e];
    const float w = ew[e];
    const float v = h[(long)s * OUT_F + lane] * w;
    atomicAdd(&out[(long)d * OUT_F + lane], v);
    if (lane == 0) atomicAdd(&cnt[d], 1.0f);
}

__global__ __launch_bounds__(256) void final_k(float* __restrict__ out,
                                               const float* __restrict__ cnt,
                                               const float* __restrict__ bias) {
    const int tid = blockIdx.x * 256 + threadIdx.x;
    if (tid >= N_NODES * OUT_F) return;
    const int n = tid >> 6;
    const int f = tid & 63;
    float c = cnt[n];
    if (c < 1.0f) c = 1.0f;
    float v = out[tid] / c + bias[f];
    out[tid] = v > 0.0f ? v : 0.0f;
}

extern "C" void kernel_launch(void* const* d_in, const int* in_sizes, int n_in,
                              void* d_out, int out_size, void* d_ws, size_t ws_size,
                              hipStream_t stream) {
    const float* x    = (const float*)d_in[0];   // [N_NODES, IN_F]
    const float* w    = (const float*)d_in[1];   // [IN_F, OUT_F]
    const float* bias = (const float*)d_in[2];   // [OUT_F]
    const float* ew   = (const float*)d_in[3];   // [N_EDGES]
    const int*   ei   = (const int*)d_in[4];     // [2, N_EDGES] as int32

    float* out = (float*)d_out;
    const int* src = ei;
    const int* dst = ei + N_EDGES;

    // Workspace layout (bytes):
    char* ws = (char*)d_ws;
    float* h     = (float*)(ws);                                   // 25.6 MB
    int*   cnt   = (int*)(ws + 25600000);                          // 400 KB
    int*   start = (int*)(ws + 26000000);                          // 400 KB
    int*   bpos  = (int*)(ws + 26400000);                          // ~3.2 KB
    int*   bsum  = (int*)(ws + 26800000);                          // 1 KB
    uint2* recs  = (uint2*)(ws + 26801024);                        // 10 MB
    const size_t WS_NEEDED = 26801024 + (size_t)N_EDGES * sizeof(uint2);

    gemm2_k<<<N_NODES / GR, 256, 0, stream>>>(x, w, h);                       // 3125

    if (ws_size >= WS_NEEDED) {
        // Bucketed gather path: no output atomics, single-pass scatter.
        hipMemsetAsync(cnt, 0, N_NODES * sizeof(int), stream);
        hist_k<<<(N_EDGES + 255) / 256, 256, 0, stream>>>(dst, cnt);          // 4883
        scan1_k<<<NSCAN_BLOCKS, 256, 0, stream>>>(cnt, start, bsum);          // 98
        scan2_k<<<1, 128, 0, stream>>>(bsum);
        scan3_k<<<(N_NODES + 255) / 256, 256, 0, stream>>>(start, bpos, bsum);// 391
        bscatter_k<<<(N_EDGES + 255) / 256, 256, 0, stream>>>(src, dst, ew, bpos, recs);
        accum_lds_k<<<NBUCK, 256, 0, stream>>>(h, recs, start, cnt, bias, out); // 782
    } else {
        // Fallback: atomic scatter (round-1 proven, 26 MB workspace).
        float* fcnt = (float*)cnt;
        hipMemsetAsync(out, 0, (size_t)N_NODES * OUT_F * sizeof(float), stream);
        hipMemsetAsync(fcnt, 0, N_NODES * sizeof(float), stream);
        scatter_k<<<(N_EDGES + 3) / 4, 256, 0, stream>>>(h, ew, src, dst, out, fcnt);
        final_k<<<(N_NODES * OUT_F + 255) / 256, 256, 0, stream>>>(out, fcnt, bias);
    }
}

// Round 14
// 327.941 us; speedup vs baseline: 3.1007x; 3.1007x over previous
//
#include <hip/hip_runtime.h>

#define N_NODES 100000
#define N_EDGES 1250000
#define IN_F 128
#define OUT_F 64

// ---------------------------------------------------------------------------
// Kernel 1: h = x @ W  (fp32, register-tiled 64x64).
// 256 threads: thread = (rowg = t>>4, colg = t&15), computes 4 rows x 4 cols.
// Per 4-k chunk: 4 x-ds_read_b128 + 4 W-ds_read_b128 -> 64 FMAs (8 FMA/LDS;
// old gemm2 was 2.67 -> LDS-instruction-bound at ~95us inferred).
// x LDS uses per-row rotation swizzle (k4' = (k4+row)&31): the 4 row-reads
// per step then alias only 2-way (free, m136). W reads: col4-contiguous,
// broadcast over rowg -> free. Total LDS 64KB -> 2 blocks/CU.
// ---------------------------------------------------------------------------
#define TM 64
__global__ __launch_bounds__(256) void gemm3_k(const float* __restrict__ x,
                                               const float* __restrict__ w,
                                               float* __restrict__ h) {
    __shared__ float wlds[IN_F * OUT_F];   // 32 KB, [k][col]
    __shared__ float xlds[TM * IN_F];      // 32 KB, row-rotated float4 layout
    const int t = threadIdx.x;
    const int row0 = blockIdx.x * TM;

    // Load W (8192 floats = 2048 float4), coalesced, linear.
    const float4* w4p = (const float4*)w;
    float4* wl4 = (float4*)wlds;
    #pragma unroll
    for (int i = 0; i < 8; ++i) wl4[t + i * 256] = w4p[t + i * 256];

    // Load x tile: 64 rows x 32 float4; store float4 (r, k4) at rotated col.
    #pragma unroll
    for (int i = 0; i < 8; ++i) {
        const int idx = t + i * 256;       // float4 index in 64x32 tile
        const int r   = idx >> 5;
        const int k4  = idx & 31;
        float4 v = make_float4(0.f, 0.f, 0.f, 0.f);
        if (row0 + r < N_NODES)
            v = ((const float4*)(x + (size_t)(row0 + r) * IN_F))[k4];
        const int k4s = (k4 + r) & 31;     // rotation swizzle
        *(float4*)&xlds[r * IN_F + k4s * 4] = v;
    }
    __syncthreads();

    const int colg = t & 15;
    const int rowg = t >> 4;
    float acc[4][4];
    #pragma unroll
    for (int i = 0; i < 4; ++i)
        #pragma unroll
        for (int j = 0; j < 4; ++j) acc[i][j] = 0.f;

    #pragma unroll 8
    for (int k4 = 0; k4 < 32; ++k4) {
        float4 wv[4];
        #pragma unroll
        for (int kk = 0; kk < 4; ++kk)
            wv[kk] = *(const float4*)&wlds[(k4 * 4 + kk) * OUT_F + colg * 4];
        #pragma unroll
        for (int i = 0; i < 4; ++i) {
            const int r = rowg * 4 + i;
            const int k4s = (k4 + r) & 31;           // same rotation on read
            const float4 xv = *(const float4*)&xlds[r * IN_F + k4s * 4];
            acc[i][0] += xv.x * wv[0].x + xv.y * wv[1].x + xv.z * wv[2].x + xv.w * wv[3].x;
            acc[i][1] += xv.x * wv[0].y + xv.y * wv[1].y + xv.z * wv[2].y + xv.w * wv[3].y;
            acc[i][2] += xv.x * wv[0].z + xv.y * wv[1].z + xv.z * wv[2].z + xv.w * wv[3].z;
            acc[i][3] += xv.x * wv[0].w + xv.y * wv[1].w + xv.z * wv[2].w + xv.w * wv[3].w;
        }
    }

    #pragma unroll
    for (int i = 0; i < 4; ++i) {
        const int r = row0 + rowg * 4 + i;
        if (r < N_NODES) {
            float4 v = make_float4(acc[i][0], acc[i][1], acc[i][2], acc[i][3]);
            *(float4*)&h[(size_t)r * OUT_F + colg * 4] = v;
        }
    }
}

// ---------------------------------------------------------------------------
// Counting sort of edges by dst: histogram -> 3-step exclusive scan -> bucket.
// (Round-9 proven: bucket_k 95us, accum_k 58us.)
// ---------------------------------------------------------------------------
__global__ __launch_bounds__(256) void hist_k(const int* __restrict__ dst,
                                              int* __restrict__ cnt) {
    const int e = blockIdx.x * 256 + threadIdx.x;
    if (e >= N_EDGES) return;
    atomicAdd(&cnt[dst[e]], 1);
}

#define SCAN_B 1024   // elements per scan block (256 threads x 4)
__global__ __launch_bounds__(256) void scan1_k(const int* __restrict__ cnt,
                                               int* __restrict__ start,
                                               int* __restrict__ bsum) {
    __shared__ int lds[256];
    const int t = threadIdx.x;
    const int base = blockIdx.x * SCAN_B + t * 4;
    int v0 = 0, v1 = 0, v2 = 0, v3 = 0;
    if (base + 0 < N_NODES) v0 = cnt[base + 0];
    if (base + 1 < N_NODES) v1 = cnt[base + 1];
    if (base + 2 < N_NODES) v2 = cnt[base + 2];
    if (base + 3 < N_NODES) v3 = cnt[base + 3];
    const int s = v0 + v1 + v2 + v3;
    lds[t] = s;
    __syncthreads();
    #pragma unroll
    for (int off = 1; off < 256; off <<= 1) {
        const int add = (t >= off) ? lds[t - off] : 0;
        __syncthreads();
        lds[t] += add;
        __syncthreads();
    }
    const int excl = lds[t] - s;
    if (base + 0 < N_NODES) start[base + 0] = excl;
    if (base + 1 < N_NODES) start[base + 1] = excl + v0;
    if (base + 2 < N_NODES) start[base + 2] = excl + v0 + v1;
    if (base + 3 < N_NODES) start[base + 3] = excl + v0 + v1 + v2;
    if (t == 255) bsum[blockIdx.x] = lds[t];
}

#define NSCAN_BLOCKS ((N_NODES + SCAN_B - 1) / SCAN_B)   // 98
__global__ __launch_bounds__(128) void scan2_k(int* __restrict__ bsum) {
    __shared__ int lds[128];
    const int t = threadIdx.x;
    const int v = (t < NSCAN_BLOCKS) ? bsum[t] : 0;
    lds[t] = v;
    __syncthreads();
    #pragma unroll
    for (int off = 1; off < 128; off <<= 1) {
        const int add = (t >= off) ? lds[t - off] : 0;
        __syncthreads();
        lds[t] += add;
        __syncthreads();
    }
    if (t < NSCAN_BLOCKS) bsum[t] = lds[t] - v;   // exclusive
}

__global__ __launch_bounds__(256) void scan3_k(int* __restrict__ start,
                                               int* __restrict__ pos,
                                               const int* __restrict__ bsum) {
    const int i = blockIdx.x * 256 + threadIdx.x;
    if (i >= N_NODES) return;
    const int v = start[i] + bsum[i / SCAN_B];
    start[i] = v;
    pos[i] = v;
}

__global__ __launch_bounds__(256) void bucket_k(const int* __restrict__ src,
                                                const int* __restrict__ dst,
                                                const float* __restrict__ ew,
                                                int* __restrict__ pos,
                                                uint2* __restrict__ pairs) {
    const int e = blockIdx.x * 256 + threadIdx.x;
    if (e >= N_EDGES) return;
    const int d = dst[e];
    const int p = atomicAdd(&pos[d], 1);
    pairs[p] = make_uint2((unsigned)src[e], __float_as_uint(ew[e]));
}

// ---------------------------------------------------------------------------
// Per-node gather-accumulate + fused finalize (div/bias/relu).
// Quarter-wave per edge-slot; round-10 measured 58us @ 68% occupancy.
// ---------------------------------------------------------------------------
__global__ __launch_bounds__(256) void accum_k(const float* __restrict__ h,
                                               const uint2* __restrict__ pairs,
                                               const int* __restrict__ start,
                                               const int* __restrict__ cnt,
                                               const float* __restrict__ bias,
                                               float* __restrict__ out) {
    const int node = blockIdx.x * 4 + (threadIdx.x >> 6);
    const int lane = threadIdx.x & 63;
    const int q  = lane >> 4;
    const int ql = lane & 15;
    const int s0 = start[node];
    const int c  = cnt[node];

    float4 acc = make_float4(0.f, 0.f, 0.f, 0.f);
    for (int i = s0 + q; i < s0 + c; i += 4) {
        const uint2 pr = pairs[i];
        const float wgt = __uint_as_float(pr.y);
        const float4 hv = ((const float4*)(h + (size_t)pr.x * OUT_F))[ql];
        acc.x += hv.x * wgt;
        acc.y += hv.y * wgt;
        acc.z += hv.z * wgt;
        acc.w += hv.w * wgt;
    }

    #pragma unroll
    for (int m = 16; m <= 32; m <<= 1) {
        acc.x += __shfl_xor(acc.x, m, 64);
        acc.y += __shfl_xor(acc.y, m, 64);
        acc.z += __shfl_xor(acc.z, m, 64);
        acc.w += __shfl_xor(acc.w, m, 64);
    }

    if (q == 0) {
        float cf = (float)c;
        if (cf < 1.f) cf = 1.f;
        const float inv = 1.0f / cf;
        const float4 b = ((const float4*)bias)[ql];
        float4 v;
        v.x = acc.x * inv + b.x;
        v.y = acc.y * inv + b.y;
        v.z = acc.z * inv + b.z;
        v.w = acc.w * inv + b.w;
        v.x = v.x > 0.f ? v.x : 0.f;
        v.y = v.y > 0.f ? v.y : 0.f;
        v.z = v.z > 0.f ? v.z : 0.f;
        v.w = v.w > 0.f ? v.w : 0.f;
        ((float4*)(out + (size_t)node * OUT_F))[ql] = v;
    }
}

// ---------------------------------------------------------------------------
// Fallback path (round-1 proven): atomic scatter + finalize. Used only if
// ws_size is too small for the sort path.
// ---------------------------------------------------------------------------
__global__ __launch_bounds__(256) void scatter_k(const float* __restrict__ h,
                                                 const float* __restrict__ ew,
                                                 const int* __restrict__ src,
                                                 const int* __restrict__ dst,
                                                 float* __restrict__ out,
                                                 float* __restrict__ cnt) {
    const int e = blockIdx.x * 4 + (threadIdx.x >> 6);
    if (e >= N_EDGES) return;
    const int lane = threadIdx.x & 63;
    const int   s = src[e];
    const int   d = dst[e];
    const float w = ew[e];
    const float v = h[(long)s * OUT_F + lane] * w;
    atomicAdd(&out[(long)d * OUT_F + lane], v);
    if (lane == 0) atomicAdd(&cnt[d], 1.0f);
}

__global__ __launch_bounds__(256) void final_k(float* __restrict__ out,
                                               const float* __restrict__ cnt,
                                               const float* __restrict__ bias) {
    const int tid = blockIdx.x * 256 + threadIdx.x;
    if (tid >= N_NODES * OUT_F) return;
    const int n = tid >> 6;
    const int f = tid & 63;
    float c = cnt[n];
    if (c < 1.0f) c = 1.0f;
    float v = out[tid] / c + bias[f];
    out[tid] = v > 0.0f ? v : 0.0f;
}

extern "C" void kernel_launch(void* const* d_in, const int* in_sizes, int n_in,
                              void* d_out, int out_size, void* d_ws, size_t ws_size,
                              hipStream_t stream) {
    const float* x    = (const float*)d_in[0];   // [N_NODES, IN_F]
    const float* w    = (const float*)d_in[1];   // [IN_F, OUT_F]
    const float* bias = (const float*)d_in[2];   // [OUT_F]
    const float* ew   = (const float*)d_in[3];   // [N_EDGES]
    const int*   ei   = (const int*)d_in[4];     // [2, N_EDGES] as int32

    float* out = (float*)d_out;
    const int* src = ei;
    const int* dst = ei + N_EDGES;

    // Workspace layout (bytes):
    char* ws = (char*)d_ws;
    float* h     = (float*)(ws);                                   // 25.6 MB
    int*   cnt   = (int*)(ws + 25600000);                          // 400 KB
    int*   start = (int*)(ws + 26000000);                          // 400 KB
    int*   pos   = (int*)(ws + 26400000);                          // 400 KB
    int*   bsum  = (int*)(ws + 26800000);                          // 1 KB
    uint2* pairs = (uint2*)(ws + 26801024);                        // 10 MB
    const size_t WS_NEEDED = 26801024 + (size_t)N_EDGES * sizeof(uint2);

    gemm3_k<<<(N_NODES + TM - 1) / TM, 256, 0, stream>>>(x, w, h);            // 1563

    if (ws_size >= WS_NEEDED) {
        // Sorted gather path: no output atomics.
        hipMemsetAsync(cnt, 0, N_NODES * sizeof(int), stream);
        hist_k<<<(N_EDGES + 255) / 256, 256, 0, stream>>>(dst, cnt);          // 4883
        scan1_k<<<NSCAN_BLOCKS, 256, 0, stream>>>(cnt, start, bsum);          // 98
        scan2_k<<<1, 128, 0, stream>>>(bsum);
        scan3_k<<<(N_NODES + 255) / 256, 256, 0, stream>>>(start, pos, bsum); // 391
        bucket_k<<<(N_EDGES + 255) / 256, 256, 0, stream>>>(src, dst, ew, pos, pairs);
        accum_k<<<N_NODES / 4, 256, 0, stream>>>(h, pairs, start, cnt, bias, out);
    } else {
        // Fallback: atomic scatter (round-1 proven, 26 MB workspace).
        float* fcnt = (float*)cnt;
        hipMemsetAsync(out, 0, (size_t)N_NODES * OUT_F * sizeof(float), stream);
        hipMemsetAsync(fcnt, 0, N_NODES * sizeof(float), stream);
        scatter_k<<<(N_EDGES + 3) / 4, 256, 0, stream>>>(h, ew, src, dst, out, fcnt);
        final_k<<<(N_NODES * OUT_F + 255) / 256, 256, 0, stream>>>(out, fcnt, bias);
    }
}